// Round 9
// baseline (333.949 us; speedup 1.0000x reference)
//
#include <hip/hip_runtime.h>
#include <hip/hip_bf16.h>

#define NEG (-1e30f)
#define M_ROWS 8000   // B*T = 16*500
#define N_COLS 5000   // V
#define K_DIM  256    // D
#define T_LEN  500
#define T_PAD  512    // lgT inner stride (t), f16 elems
#define B_SZ   16
#define L_LAB  50
#define LDS_STR 72    // gemm LDS pad (f16 elems)
#define NBLK   768    // persistent grid: 3 blocks/CU (LDS 51.3KB -> 3 fit)
#define NTILE  2520   // 40 n-tiles x 63 m-tiles
#define LOG2E  1.4426950408889634f
#define LN2    0.6931471805599453f

typedef _Float16 half8  __attribute__((ext_vector_type(8)));
typedef _Float16 half4  __attribute__((ext_vector_type(4)));
typedef _Float16 half4v __attribute__((ext_vector_type(4)));
typedef float    floatx4 __attribute__((ext_vector_type(4)));

__device__ __forceinline__ float fexp2(float x) {
#if defined(__has_builtin)
#if __has_builtin(__builtin_amdgcn_exp2f)
  return __builtin_amdgcn_exp2f(x);
#else
  return __expf(x * LN2);
#endif
#else
  return __expf(x * LN2);
#endif
}
__device__ __forceinline__ float flog2(float x) {
#if defined(__has_builtin)
#if __has_builtin(__builtin_amdgcn_logf)
  return __builtin_amdgcn_logf(x);
#else
  return __logf(x) * LOG2E;
#endif
#else
  return __logf(x) * LOG2E;
#endif
}
// cross-lane shift-down-by-1 (lane i <- lane i-1), lane0 -> 0.0, for doubles
__device__ __forceinline__ double shr1_f64(double x) {
#if defined(__has_builtin)
#if __has_builtin(__builtin_amdgcn_update_dpp)
  long long b = __double_as_longlong(x);
  int lo = (int)(b & 0xffffffffLL);
  int hi = (int)(((unsigned long long)b) >> 32);
  lo = __builtin_amdgcn_update_dpp(0, lo, 0x138 /*wave_shr:1*/, 0xf, 0xf, false);
  hi = __builtin_amdgcn_update_dpp(0, hi, 0x138 /*wave_shr:1*/, 0xf, 0xf, false);
  return __longlong_as_double(((long long)(unsigned)hi << 32) | (unsigned)lo);
#else
  return __shfl_up(x, 1);
#endif
#else
  return __shfl_up(x, 1);
#endif
}

// device-scope grid barrier; ctr memset to 0 before launch. Bounded spin so a
// co-residency failure yields a wrong answer, not a hang.
__device__ __forceinline__ void gbar(unsigned int* c) {
  __syncthreads();
  if (threadIdx.x == 0) {
    __threadfence();
    __hip_atomic_fetch_add(c, 1u, __ATOMIC_ACQ_REL, __HIP_MEMORY_SCOPE_AGENT);
    int spins = 0;
    while (__hip_atomic_load(c, __ATOMIC_ACQUIRE, __HIP_MEMORY_SCOPE_AGENT) < NBLK) {
      __builtin_amdgcn_s_sleep(16);
      if (++spins > (1 << 17)) break;   // ~50ms cap
    }
    __threadfence();
  }
  __syncthreads();
}

// ================= single fused kernel =============================================
// P0: f32->f16 convert (enc,W) + zero psum/out
// P1: persistent-tile MFMA GEMM + sumexp atomics + ballot label scatter (R7 body)
// P2: blocks 0..15: CTC DP, linear domain, f64 accumulators, odds-vs-blank LDS
__global__ __launch_bounds__(256, 3) void k_fused(
    const float* __restrict__ enc, const float* __restrict__ W,
    const float* __restrict__ bias, const int* __restrict__ y,
    const int* __restrict__ enc_lens, const int* __restrict__ y_lens,
    _Float16* __restrict__ ench, _Float16* __restrict__ wh,
    float* __restrict__ psum, _Float16* __restrict__ lgT,
    unsigned int* __restrict__ ctr, float* __restrict__ out) {
  __shared__ __align__(16) char smem[51264];   // union: gemm 36,864 | dp 51,200+20
  const int tid = threadIdx.x;
  const int bid = blockIdx.x;

  // ---------------- P0: convert + zero ----------------
  {
    int gidx = bid * 256 + tid;
    if (gidx == 0) out[0] = 0.0f;
    if (gidx < M_ROWS) psum[gidx] = 0.0f;   // 8000 < 196608 threads
    for (int i = gidx; i < 832000; i += NBLK * 256) {
      if (i < 512000) {
        float4 v = ((const float4*)enc)[i];
        half4v o = {(_Float16)v.x, (_Float16)v.y, (_Float16)v.z, (_Float16)v.w};
        ((half4v*)ench)[i] = o;
      } else {
        int k = i - 512000;
        float4 v = ((const float4*)W)[k];
        half4v o = {(_Float16)v.x, (_Float16)v.y, (_Float16)v.z, (_Float16)v.w};
        ((half4v*)wh)[k] = o;
      }
    }
  }
  gbar(ctr + 0);

  // ---------------- P1: gemm tiles (R7 body, register staging) ----------------
  {
    _Float16* As = (_Float16*)smem;              // 128*72*2 = 18,432 B
    _Float16* Bs = (_Float16*)(smem + 18432);    // 18,432 B
    const int lane = tid & 63;
    const int wid = tid >> 6;
    const int wave_m = wid & 1, wave_n = wid >> 1;
    const int l15 = lane & 15, quad = lane >> 4;

    for (int tile = bid; tile < NTILE; tile += NBLK) {
      const int n0 = (tile % 40) * 128, m0 = (tile / 40) * 128;

      floatx4 acc[4][4];
      floatx4 zz = {0.f, 0.f, 0.f, 0.f};
      #pragma unroll
      for (int mi = 0; mi < 4; ++mi)
        #pragma unroll
        for (int ni = 0; ni < 4; ++ni) acc[mi][ni] = zz;

      for (int kk = 0; kk < K_DIM; kk += 64) {
        #pragma unroll
        for (int r = 0; r < 4; ++r) {
          int flat = r * 256 + tid;
          int row = flat >> 3, c8 = flat & 7;
          int ga = m0 + row; if (ga > M_ROWS - 1) ga = M_ROWS - 1;
          int4 av = *(const int4*)(ench + (size_t)ga * K_DIM + kk + c8 * 8);
          *(int4*)(As + row * LDS_STR + c8 * 8) = av;
          int gb = n0 + row; if (gb > N_COLS - 1) gb = N_COLS - 1;
          int4 bv = *(const int4*)(wh + (size_t)gb * K_DIM + kk + c8 * 8);
          *(int4*)(Bs + row * LDS_STR + c8 * 8) = bv;
        }
        __syncthreads();
        #pragma unroll
        for (int ko = 0; ko < 64; ko += 32) {
          half8 af[4], bf[4];
          #pragma unroll
          for (int mi = 0; mi < 4; ++mi)
            af[mi] = *(const half8*)(As + (wave_m * 64 + mi * 16 + l15) * LDS_STR + ko + quad * 8);
          #pragma unroll
          for (int ni = 0; ni < 4; ++ni)
            bf[ni] = *(const half8*)(Bs + (wave_n * 64 + ni * 16 + l15) * LDS_STR + ko + quad * 8);
          #pragma unroll
          for (int mi = 0; mi < 4; ++mi)
            #pragma unroll
            for (int ni = 0; ni < 4; ++ni)
              acc[mi][ni] = __builtin_amdgcn_mfma_f32_16x16x32_f16(af[mi], bf[ni], acc[mi][ni], 0, 0, 0);
        }
        __syncthreads();
      }

      float bvv[4]; bool cok[4];
      #pragma unroll
      for (int ni = 0; ni < 4; ++ni) {
        int col = n0 + wave_n * 64 + ni * 16 + l15;
        cok[ni] = (col < N_COLS);
        bvv[ni] = cok[ni] ? bias[col] : 0.f;
      }

      // ballot scatter of label logits (f16, base-2 pre-scaled)
      const int nbase = n0 + wave_n * 64;
      const int mbase = m0 + wave_m * 64;
      int b_lo = mbase / T_LEN;
      int b_hi = (mbase + 63) / T_LEN;
      if (b_hi > B_SZ - 1) b_hi = B_SZ - 1;
      for (int b = b_lo; b <= b_hi; ++b) {
        int v_l = 0x40000000;
        if (lane <= 50) v_l = (lane == 0) ? 0 : y[b * L_LAB + lane - 1];
        int dv_l = v_l - nbase;
        unsigned long long mask = __ballot(dv_l >= 0 && dv_l < 64);
        while (mask) {
          int j = (int)__builtin_ctzll(mask);
          mask &= mask - 1;
          int dv = __shfl(dv_l, j);
          int ni = dv >> 4;
          float bb = bvv[0];
          bb = (ni == 1) ? bvv[1] : bb;
          bb = (ni == 2) ? bvv[2] : bb;
          bb = (ni == 3) ? bvv[3] : bb;
          if ((dv & 15) == l15) {
            #pragma unroll
            for (int mi = 0; mi < 4; ++mi) {
              #pragma unroll
              for (int r = 0; r < 4; ++r) {
                float val = acc[mi][0][r];
                val = (ni == 1) ? acc[mi][1][r] : val;
                val = (ni == 2) ? acc[mi][2][r] : val;
                val = (ni == 3) ? acc[mi][3][r] : val;
                int grow = mbase + mi * 16 + quad * 4 + r;
                int t = grow - b * T_LEN;
                if (t >= 0 && t < T_LEN && grow < M_ROWS)
                  lgT[((size_t)b * 51 + j) * T_PAD + t] = (_Float16)((val + bb) * LOG2E);
              }
            }
          }
        }
      }

      // per-row sumexp partials
      #pragma unroll
      for (int mi = 0; mi < 4; ++mi) {
        #pragma unroll
        for (int r = 0; r < 4; ++r) {
          int grow = mbase + mi * 16 + quad * 4 + r;
          float se = 0.f;
          se += cok[0] ? fexp2((acc[mi][0][r] + bvv[0]) * LOG2E) : 0.f;
          se += cok[1] ? fexp2((acc[mi][1][r] + bvv[1]) * LOG2E) : 0.f;
          se += cok[2] ? fexp2((acc[mi][2][r] + bvv[2]) * LOG2E) : 0.f;
          se += cok[3] ? fexp2((acc[mi][3][r] + bvv[3]) * LOG2E) : 0.f;
          #pragma unroll
          for (int d = 1; d < 16; d <<= 1) se += __shfl_xor(se, d);
          if (l15 == 0 && grow < M_ROWS) atomicAdd(&psum[grow], se);
        }
      }
    }
  }
  gbar(ctr + 1);

  // ---------------- P2: CTC DP, blocks 0..15 ----------------
  if (bid < B_SZ) {
    const int b = bid;
    const int Tb = enc_lens[b], yl = y_lens[b];
    _Float16* sQ = (_Float16*)smem;              // 50 rows x 512 f16 = 51,200 B
    float* sRed = (float*)(smem + 51200);        // 5 floats
    const _Float16* g = lgT + (size_t)b * 51 * T_PAD;

    // stage q(label j+1, t) = 2^(l2[j+1][t] - l2[0][t]) as f16
    #pragma unroll
    for (int k = 0; k < 13; ++k) {
      int idx = tid + k * 256;
      if (idx < 50 * 64) {
        int row = idx >> 6, c8 = idx & 63;
        half8 h = *(const half8*)(g + (size_t)(row + 1) * T_PAD + c8 * 8);
        half8 hb = *(const half8*)(g + c8 * 8);
        half8 o;
        #pragma unroll
        for (int e = 0; e < 8; ++e)
          o[e] = (_Float16)fminf(fexp2((float)h[e] - (float)hb[e]), 60000.0f);
        *(half8*)(sQ + row * T_PAD + c8 * 8) = o;
      }
    }

    // parallel: sum over t<Tb of (l2_blank[t] - log2(psum[b,t]))
    float sl2 = 0.f;
    for (int t = tid; t < Tb; t += 256)
      sl2 += (float)g[t] - flog2(psum[b * T_LEN + t]);
    #pragma unroll
    for (int d = 1; d < 64; d <<= 1) sl2 += __shfl_xor(sl2, d);
    if ((tid & 63) == 0) sRed[1 + (tid >> 6)] = sl2;
    __syncthreads();
    const float base2 = sRed[1] + sRed[2] + sRed[3] + sRed[4];

    if (tid < 64) {
      const int i = tid;
      const int rw = (i < 50) ? i : 49;
      const _Float16* ow = sQ + rw * T_PAD;
      const bool v1 = (i <= 49);
      const bool lane0 = (i == 0);
      const bool skip1 = (i >= 1 && i <= 49) && (y[b * L_LAB + i] != y[b * L_LAB + i - 1]);

      auto ld4 = [&](int t) -> double4 {
        half4 h = *(const half4*)(ow + t);
        double4 d;
        if (v1) { d.x = (float)h[0]; d.y = (float)h[1]; d.z = (float)h[2]; d.w = (float)h[3]; }
        else    { d.x = 0.0; d.y = 0.0; d.z = 0.0; d.w = 0.0; }
        return d;
      };
      double4 qA = ld4(0), qB = ld4(4), qC = ld4(8), qD = ld4(12);

      double a0 = lane0 ? 1.0 : 0.0;
      double a1 = lane0 ? qA.x : 0.0;

      auto step = [&](double qd) {
        double p1 = shr1_f64(a1);
        p1 = lane0 ? 0.0 : p1;
        double na0 = a0 + p1;
        double t3 = skip1 ? p1 : 0.0;
        double na1 = (a1 + a0 + t3) * qd;
        a0 = na0; a1 = na1;
      };

      step(qA.y); step(qA.z); step(qA.w);
      double4 cur = qB, nxt = qC, nn = qD;
      int t = 4;
      while (t + 4 <= Tb) {
        double4 p = ld4(t + 12);   // max index 511 < 512, in-bounds
        step(cur.x); step(cur.y); step(cur.z); step(cur.w);
        cur = nxt; nxt = nn; nn = p;
        t += 4;
      }
      if (t < Tb) { step(cur.x); ++t; }
      if (t < Tb) { step(cur.y); ++t; }
      if (t < Tb) { step(cur.z); ++t; }

      double ea = __shfl(a0, yl);       // s = 2*yl
      double eb = __shfl(a1, yl - 1);   // s = 2*yl-1
      if (lane0) {
        double s = ea + eb;
        long long bb = __double_as_longlong(s);
        int e2 = (int)((bb >> 52) & 2047) - 1023;
        double mant = __longlong_as_double((bb & 0x000FFFFFFFFFFFFFLL) | 0x3FF0000000000000LL);
        float l2fin = (float)e2 + flog2((float)mant);
        atomicAdd(out, -(base2 + l2fin) * LN2 * (1.0f / (float)B_SZ));
      }
    }
  }
}

extern "C" void kernel_launch(void* const* d_in, const int* in_sizes, int n_in,
                              void* d_out, int out_size, void* d_ws, size_t ws_size,
                              hipStream_t stream) {
  (void)in_sizes; (void)n_in; (void)out_size; (void)ws_size;
  const float* enc      = (const float*)d_in[0];   // [16][500][256]
  const int*   enc_lens = (const int*)d_in[1];     // [16]
  const int*   y        = (const int*)d_in[2];     // [16][50]
  const int*   y_lens   = (const int*)d_in[3];     // [16]
  const float* W        = (const float*)d_in[4];   // [5000][256]
  const float* bias     = (const float*)d_in[5];   // [5000]
  float* out = (float*)d_out;

  char* ws = (char*)d_ws;
  _Float16* ench = (_Float16*)(ws + 0);            // 4,096,000 B
  _Float16* wh   = (_Float16*)(ws + 4096000);      // 2,560,000 B
  float* psum    = (float*)(ws + 6656000);         //    32,000 B
  _Float16* lgT  = (_Float16*)(ws + 6688000);      //   835,584 B
  unsigned int* ctr = (unsigned int*)(ws + 7523584); //     64 B

  hipMemsetAsync(ctr, 0, 64, stream);
  k_fused<<<NBLK, 256, 0, stream>>>(enc, W, bias, y, enc_lens, y_lens,
                                    ench, wh, psum, lgT, ctr, out);
}

// Round 10
// 323.173 us; speedup vs baseline: 1.0333x; 1.0333x over previous
//
#include <hip/hip_runtime.h>
#include <hip/hip_bf16.h>

#define NEG (-1e30f)
#define M_ROWS 8000   // B*T = 16*500
#define N_COLS 5000   // V
#define K_DIM  256    // D
#define T_LEN  500
#define T_PAD  512    // lgT inner stride (t), f16 elems
#define B_SZ   16
#define L_LAB  50
#define LDS_STR 72    // gemm LDS pad (f16 elems)
#define Q_STR  520    // P2 sQ row stride (f16): 1040B -> b64 reads 8-way, not 64-way
#define NBLK   768    // persistent grid: 3 blocks/CU (register-bound at 3 anyway)
#define NTILE  2520   // 40 n-tiles x 63 m-tiles
#define LOG2E  1.4426950408889634f
#define LN2    0.6931471805599453f

typedef _Float16 half8  __attribute__((ext_vector_type(8)));
typedef _Float16 half4  __attribute__((ext_vector_type(4)));
typedef _Float16 half4v __attribute__((ext_vector_type(4)));
typedef float    floatx4 __attribute__((ext_vector_type(4)));

__device__ __forceinline__ float fexp2(float x) {
#if defined(__has_builtin)
#if __has_builtin(__builtin_amdgcn_exp2f)
  return __builtin_amdgcn_exp2f(x);
#else
  return __expf(x * LN2);
#endif
#else
  return __expf(x * LN2);
#endif
}
__device__ __forceinline__ float flog2(float x) {
#if defined(__has_builtin)
#if __has_builtin(__builtin_amdgcn_logf)
  return __builtin_amdgcn_logf(x);
#else
  return __logf(x) * LOG2E;
#endif
#else
  return __logf(x) * LOG2E;
#endif
}
// cross-lane shift-down-by-1 (lane i <- lane i-1), lane0 -> 0.0, for doubles
__device__ __forceinline__ double shr1_f64(double x) {
#if defined(__has_builtin)
#if __has_builtin(__builtin_amdgcn_update_dpp)
  long long b = __double_as_longlong(x);
  int lo = (int)(b & 0xffffffffLL);
  int hi = (int)(((unsigned long long)b) >> 32);
  lo = __builtin_amdgcn_update_dpp(0, lo, 0x138 /*wave_shr:1*/, 0xf, 0xf, false);
  hi = __builtin_amdgcn_update_dpp(0, hi, 0x138 /*wave_shr:1*/, 0xf, 0xf, false);
  return __longlong_as_double(((long long)(unsigned)hi << 32) | (unsigned)lo);
#else
  return __shfl_up(x, 1);
#endif
#else
  return __shfl_up(x, 1);
#endif
}

// Grid barrier. RELEASE on arrival (one buffer_wbl2 per block — needed for
// cross-XCD visibility), RELAXED spin (no cache maintenance!), ONE acquire after
// exit (one buffer_inv). R9's bug: ACQUIRE in the spin loop = L2 invalidate per
// iteration from every waiting block -> starved the computing blocks' L2.
__device__ __forceinline__ void gbar(unsigned int* c) {
  __syncthreads();
  if (threadIdx.x == 0) {
    __hip_atomic_fetch_add(c, 1u, __ATOMIC_RELEASE, __HIP_MEMORY_SCOPE_AGENT);
    int spins = 0;
    while (__hip_atomic_load(c, __ATOMIC_RELAXED, __HIP_MEMORY_SCOPE_AGENT) < NBLK) {
      __builtin_amdgcn_s_sleep(16);
      if (++spins > (1 << 17)) break;   // bounded: fail visibly, not hang
    }
    (void)__hip_atomic_load(c, __ATOMIC_ACQUIRE, __HIP_MEMORY_SCOPE_AGENT);
  }
  __syncthreads();
}

// ================= single fused kernel =============================================
// P0: f32->f16 convert (enc,W) + zero psum/out
// P1: MFMA GEMM tiles via dynamic stealing + sumexp atomics + ballot label scatter
// P2: blocks 0..15: CTC DP, linear domain, f64 accumulators, odds-vs-blank LDS
__global__ __launch_bounds__(256, 3) void k_fused(
    const float* __restrict__ enc, const float* __restrict__ W,
    const float* __restrict__ bias, const int* __restrict__ y,
    const int* __restrict__ enc_lens, const int* __restrict__ y_lens,
    _Float16* __restrict__ ench, _Float16* __restrict__ wh,
    float* __restrict__ psum, _Float16* __restrict__ lgT,
    unsigned int* __restrict__ ctr, float* __restrict__ out) {
  __shared__ __align__(16) char smem[52032];  // gemm: 36,864 | dp: sQ 52,000 + sRed
  const int tid = threadIdx.x;
  const int bid = blockIdx.x;

  // ---------------- P0: convert + zero ----------------
  {
    int gidx = bid * 256 + tid;
    if (gidx == 0) out[0] = 0.0f;
    if (gidx < M_ROWS) psum[gidx] = 0.0f;
    for (int i = gidx; i < 832000; i += NBLK * 256) {
      if (i < 512000) {
        float4 v = ((const float4*)enc)[i];
        half4v o = {(_Float16)v.x, (_Float16)v.y, (_Float16)v.z, (_Float16)v.w};
        ((half4v*)ench)[i] = o;
      } else {
        int k = i - 512000;
        float4 v = ((const float4*)W)[k];
        half4v o = {(_Float16)v.x, (_Float16)v.y, (_Float16)v.z, (_Float16)v.w};
        ((half4v*)wh)[k] = o;
      }
    }
  }
  gbar(ctr + 0);

  // ---------------- P1: gemm tiles, dynamic stealing ----------------
  {
    _Float16* As = (_Float16*)smem;              // 18,432 B
    _Float16* Bs = (_Float16*)(smem + 18432);    // 18,432 B
    unsigned int* sTile = (unsigned int*)(smem + 52024);
    const int lane = tid & 63;
    const int wid = tid >> 6;
    const int wave_m = wid & 1, wave_n = wid >> 1;
    const int l15 = lane & 15, quad = lane >> 4;

    for (;;) {
      if (tid == 0)
        sTile[0] = __hip_atomic_fetch_add(ctr + 2, 1u, __ATOMIC_RELAXED,
                                          __HIP_MEMORY_SCOPE_AGENT);
      __syncthreads();
      const unsigned tile = sTile[0];
      if (tile >= NTILE) break;   // no barrier needed: sTile rewritten only after
                                  // the k-loop's first __syncthreads next iter
      const int n0 = (tile % 40) * 128, m0 = ((int)tile / 40) * 128;

      floatx4 acc[4][4];
      floatx4 zz = {0.f, 0.f, 0.f, 0.f};
      #pragma unroll
      for (int mi = 0; mi < 4; ++mi)
        #pragma unroll
        for (int ni = 0; ni < 4; ++ni) acc[mi][ni] = zz;

      for (int kk = 0; kk < K_DIM; kk += 64) {
        #pragma unroll
        for (int r = 0; r < 4; ++r) {
          int flat = r * 256 + tid;
          int row = flat >> 3, c8 = flat & 7;
          int ga = m0 + row; if (ga > M_ROWS - 1) ga = M_ROWS - 1;
          int4 av = *(const int4*)(ench + (size_t)ga * K_DIM + kk + c8 * 8);
          *(int4*)(As + row * LDS_STR + c8 * 8) = av;
          int gb = n0 + row; if (gb > N_COLS - 1) gb = N_COLS - 1;
          int4 bv = *(const int4*)(wh + (size_t)gb * K_DIM + kk + c8 * 8);
          *(int4*)(Bs + row * LDS_STR + c8 * 8) = bv;
        }
        __syncthreads();
        #pragma unroll
        for (int ko = 0; ko < 64; ko += 32) {
          half8 af[4], bf[4];
          #pragma unroll
          for (int mi = 0; mi < 4; ++mi)
            af[mi] = *(const half8*)(As + (wave_m * 64 + mi * 16 + l15) * LDS_STR + ko + quad * 8);
          #pragma unroll
          for (int ni = 0; ni < 4; ++ni)
            bf[ni] = *(const half8*)(Bs + (wave_n * 64 + ni * 16 + l15) * LDS_STR + ko + quad * 8);
          #pragma unroll
          for (int mi = 0; mi < 4; ++mi)
            #pragma unroll
            for (int ni = 0; ni < 4; ++ni)
              acc[mi][ni] = __builtin_amdgcn_mfma_f32_16x16x32_f16(af[mi], bf[ni], acc[mi][ni], 0, 0, 0);
        }
        __syncthreads();
      }

      float bvv[4]; bool cok[4];
      #pragma unroll
      for (int ni = 0; ni < 4; ++ni) {
        int col = n0 + wave_n * 64 + ni * 16 + l15;
        cok[ni] = (col < N_COLS);
        bvv[ni] = cok[ni] ? bias[col] : 0.f;
      }

      // ballot scatter of label logits (f16, base-2 pre-scaled)
      const int nbase = n0 + wave_n * 64;
      const int mbase = m0 + wave_m * 64;
      int b_lo = mbase / T_LEN;
      int b_hi = (mbase + 63) / T_LEN;
      if (b_hi > B_SZ - 1) b_hi = B_SZ - 1;
      for (int b = b_lo; b <= b_hi; ++b) {
        int v_l = 0x40000000;
        if (lane <= 50) v_l = (lane == 0) ? 0 : y[b * L_LAB + lane - 1];
        int dv_l = v_l - nbase;
        unsigned long long mask = __ballot(dv_l >= 0 && dv_l < 64);
        while (mask) {
          int j = (int)__builtin_ctzll(mask);
          mask &= mask - 1;
          int dv = __shfl(dv_l, j);
          int ni = dv >> 4;
          float bb = bvv[0];
          bb = (ni == 1) ? bvv[1] : bb;
          bb = (ni == 2) ? bvv[2] : bb;
          bb = (ni == 3) ? bvv[3] : bb;
          if ((dv & 15) == l15) {
            #pragma unroll
            for (int mi = 0; mi < 4; ++mi) {
              #pragma unroll
              for (int r = 0; r < 4; ++r) {
                float val = acc[mi][0][r];
                val = (ni == 1) ? acc[mi][1][r] : val;
                val = (ni == 2) ? acc[mi][2][r] : val;
                val = (ni == 3) ? acc[mi][3][r] : val;
                int grow = mbase + mi * 16 + quad * 4 + r;
                int t = grow - b * T_LEN;
                if (t >= 0 && t < T_LEN && grow < M_ROWS)
                  lgT[((size_t)b * 51 + j) * T_PAD + t] = (_Float16)((val + bb) * LOG2E);
              }
            }
          }
        }
      }

      // per-row sumexp partials
      #pragma unroll
      for (int mi = 0; mi < 4; ++mi) {
        #pragma unroll
        for (int r = 0; r < 4; ++r) {
          int grow = mbase + mi * 16 + quad * 4 + r;
          float se = 0.f;
          se += cok[0] ? fexp2((acc[mi][0][r] + bvv[0]) * LOG2E) : 0.f;
          se += cok[1] ? fexp2((acc[mi][1][r] + bvv[1]) * LOG2E) : 0.f;
          se += cok[2] ? fexp2((acc[mi][2][r] + bvv[2]) * LOG2E) : 0.f;
          se += cok[3] ? fexp2((acc[mi][3][r] + bvv[3]) * LOG2E) : 0.f;
          #pragma unroll
          for (int d = 1; d < 16; d <<= 1) se += __shfl_xor(se, d);
          if (l15 == 0 && grow < M_ROWS) atomicAdd(&psum[grow], se);
        }
      }
    }
  }
  gbar(ctr + 1);

  // ---------------- P2: CTC DP, blocks 0..15 ----------------
  if (bid < B_SZ) {
    const int b = bid;
    const int Tb = enc_lens[b], yl = y_lens[b];
    _Float16* sQ = (_Float16*)smem;              // 50 rows x Q_STR f16 = 52,000 B
    float* sRed = (float*)(smem + 52000);        // 5 floats
    const _Float16* g = lgT + (size_t)b * 51 * T_PAD;

    // stage q(label j+1, t) = 2^(l2[j+1][t] - l2[0][t]) as f16
    #pragma unroll
    for (int k = 0; k < 13; ++k) {
      int idx = tid + k * 256;
      if (idx < 50 * 64) {
        int row = idx >> 6, c8 = idx & 63;
        half8 h = *(const half8*)(g + (size_t)(row + 1) * T_PAD + c8 * 8);
        half8 hb = *(const half8*)(g + c8 * 8);
        half8 o;
        #pragma unroll
        for (int e = 0; e < 8; ++e)
          o[e] = (_Float16)fminf(fexp2((float)h[e] - (float)hb[e]), 60000.0f);
        *(half8*)(sQ + row * Q_STR + c8 * 8) = o;
      }
    }

    // parallel: sum over t<Tb of (l2_blank[t] - log2(psum[b,t]))
    float sl2 = 0.f;
    for (int t = tid; t < Tb; t += 256)
      sl2 += (float)g[t] - flog2(psum[b * T_LEN + t]);
    #pragma unroll
    for (int d = 1; d < 64; d <<= 1) sl2 += __shfl_xor(sl2, d);
    if ((tid & 63) == 0) sRed[1 + (tid >> 6)] = sl2;
    __syncthreads();
    const float base2 = sRed[1] + sRed[2] + sRed[3] + sRed[4];

    if (tid < 64) {
      const int i = tid;
      const int rw = (i < 50) ? i : 49;
      const _Float16* ow = sQ + rw * Q_STR;
      const bool v1 = (i <= 49);
      const bool lane0 = (i == 0);
      const bool skip1 = (i >= 1 && i <= 49) && (y[b * L_LAB + i] != y[b * L_LAB + i - 1]);

      auto ld4 = [&](int t) -> double4 {
        half4 h = *(const half4*)(ow + t);
        double4 d;
        if (v1) { d.x = (float)h[0]; d.y = (float)h[1]; d.z = (float)h[2]; d.w = (float)h[3]; }
        else    { d.x = 0.0; d.y = 0.0; d.z = 0.0; d.w = 0.0; }
        return d;
      };
      double4 qA = ld4(0), qB = ld4(4), qC = ld4(8), qD = ld4(12);

      double a0 = lane0 ? 1.0 : 0.0;
      double a1 = lane0 ? qA.x : 0.0;

      auto step = [&](double qd) {
        double p1 = shr1_f64(a1);
        p1 = lane0 ? 0.0 : p1;
        double na0 = a0 + p1;
        double t3 = skip1 ? p1 : 0.0;
        double na1 = (a1 + a0 + t3) * qd;
        a0 = na0; a1 = na1;
      };

      step(qA.y); step(qA.z); step(qA.w);
      double4 cur = qB, nxt = qC, nn = qD;
      int t = 4;
      while (t + 4 <= Tb) {
        double4 p = ld4(t + 12);   // max index 511 < 512, in-bounds
        step(cur.x); step(cur.y); step(cur.z); step(cur.w);
        cur = nxt; nxt = nn; nn = p;
        t += 4;
      }
      if (t < Tb) { step(cur.x); ++t; }
      if (t < Tb) { step(cur.y); ++t; }
      if (t < Tb) { step(cur.z); ++t; }

      double ea = __shfl(a0, yl);       // s = 2*yl
      double eb = __shfl(a1, yl - 1);   // s = 2*yl-1
      if (lane0) {
        double s = ea + eb;
        long long bb = __double_as_longlong(s);
        int e2 = (int)((bb >> 52) & 2047) - 1023;
        double mant = __longlong_as_double((bb & 0x000FFFFFFFFFFFFFLL) | 0x3FF0000000000000LL);
        float l2fin = (float)e2 + flog2((float)mant);
        atomicAdd(out, -(base2 + l2fin) * LN2 * (1.0f / (float)B_SZ));
      }
    }
  }
}

extern "C" void kernel_launch(void* const* d_in, const int* in_sizes, int n_in,
                              void* d_out, int out_size, void* d_ws, size_t ws_size,
                              hipStream_t stream) {
  (void)in_sizes; (void)n_in; (void)out_size; (void)ws_size;
  const float* enc      = (const float*)d_in[0];   // [16][500][256]
  const int*   enc_lens = (const int*)d_in[1];     // [16]
  const int*   y        = (const int*)d_in[2];     // [16][50]
  const int*   y_lens   = (const int*)d_in[3];     // [16]
  const float* W        = (const float*)d_in[4];   // [5000][256]
  const float* bias     = (const float*)d_in[5];   // [5000]
  float* out = (float*)d_out;

  char* ws = (char*)d_ws;
  _Float16* ench = (_Float16*)(ws + 0);            // 4,096,000 B
  _Float16* wh   = (_Float16*)(ws + 4096000);      // 2,560,000 B
  float* psum    = (float*)(ws + 6656000);         //    32,000 B
  _Float16* lgT  = (_Float16*)(ws + 6688000);      //   835,584 B
  unsigned int* ctr = (unsigned int*)(ws + 7523584); //     64 B (ctr[2] = tile pool)

  hipMemsetAsync(ctr, 0, 64, stream);
  k_fused<<<NBLK, 256, 0, stream>>>(enc, W, bias, y, enc_lens, y_lens,
                                    ench, wh, psum, lgT, ctr, out);
}

// Round 11
// 235.862 us; speedup vs baseline: 1.4159x; 1.3702x over previous
//
#include <hip/hip_runtime.h>
#include <hip/hip_bf16.h>

#define NEG (-1e30f)
#define M_ROWS 8000   // B*T = 16*500
#define N_COLS 5000   // V
#define K_DIM  256    // D
#define T_LEN  500
#define T_PAD  512    // lgT inner stride (t), f16 elems
#define B_SZ   16
#define L_LAB  50
#define LDS_STR 72    // gemm LDS pad (f16 elems)
#define Q_STR  520    // k_dp sQ row stride (f16): b64 reads 8-way, not 64-way
#define LOG2E  1.4426950408889634f
#define LN2    0.6931471805599453f

typedef _Float16 half8  __attribute__((ext_vector_type(8)));
typedef _Float16 half4  __attribute__((ext_vector_type(4)));
typedef _Float16 half4v __attribute__((ext_vector_type(4)));
typedef float    floatx4 __attribute__((ext_vector_type(4)));

__device__ __forceinline__ float fexp2(float x) {
#if defined(__has_builtin)
#if __has_builtin(__builtin_amdgcn_exp2f)
  return __builtin_amdgcn_exp2f(x);
#else
  return __expf(x * LN2);
#endif
#else
  return __expf(x * LN2);
#endif
}
__device__ __forceinline__ float flog2(float x) {
#if defined(__has_builtin)
#if __has_builtin(__builtin_amdgcn_logf)
  return __builtin_amdgcn_logf(x);
#else
  return __logf(x) * LOG2E;
#endif
#else
  return __logf(x) * LOG2E;
#endif
}
// cross-lane shift-down-by-1 (lane i <- lane i-1), lane0 -> 0.0, for doubles
__device__ __forceinline__ double shr1_f64(double x) {
#if defined(__has_builtin)
#if __has_builtin(__builtin_amdgcn_update_dpp)
  long long b = __double_as_longlong(x);
  int lo = (int)(b & 0xffffffffLL);
  int hi = (int)(((unsigned long long)b) >> 32);
  lo = __builtin_amdgcn_update_dpp(0, lo, 0x138 /*wave_shr:1*/, 0xf, 0xf, false);
  hi = __builtin_amdgcn_update_dpp(0, hi, 0x138 /*wave_shr:1*/, 0xf, 0xf, false);
  return __longlong_as_double(((long long)(unsigned)hi << 32) | (unsigned)lo);
#else
  return __shfl_up(x, 1);
#endif
#else
  return __shfl_up(x, 1);
#endif
}

// ---------------- fused fp32->fp16 (enc + W) + zero out/psum ----------------------
__global__ void k_f2h2(const float* __restrict__ enc, const float* __restrict__ W,
                       _Float16* __restrict__ ench, _Float16* __restrict__ wh,
                       float* z, float* psum) {
  int i = blockIdx.x * blockDim.x + threadIdx.x;
  if (i == 0) z[0] = 0.0f;
  if (i < M_ROWS) psum[i] = 0.0f;
  if (i < 512000) {
    float4 v = ((const float4*)enc)[i];
    half4v o = {(_Float16)v.x, (_Float16)v.y, (_Float16)v.z, (_Float16)v.w};
    ((half4v*)ench)[i] = o;
  } else {
    int k = i - 512000;
    if (k < 320000) {
      float4 v = ((const float4*)W)[k];
      half4v o = {(_Float16)v.x, (_Float16)v.y, (_Float16)v.z, (_Float16)v.w};
      ((half4v*)wh)[k] = o;
    }
  }
}

// ---------------- MFMA GEMM, 1-deep SW pipeline + sumexp + ballot scatter ---------
// R7 structure (best measured 78us) + register software pipeline: k+1's global
// loads are issued right after the LDS-store barrier, in flight across the whole
// MFMA section (~700-900cyc) -> staging latency leaves the critical path.
__global__ __launch_bounds__(256) void k_gemm_lse(
    const _Float16* __restrict__ A, const _Float16* __restrict__ Bm,
    const float* __restrict__ bias, const int* __restrict__ y,
    float* __restrict__ psum, _Float16* __restrict__ lgT) {
  __shared__ _Float16 As[128 * LDS_STR];   // 18,432 B
  __shared__ _Float16 Bs[128 * LDS_STR];   // 18,432 B

  const int tid = threadIdx.x;
  const int lane = tid & 63;
  const int wid = tid >> 6;
  const int wave_m = wid & 1, wave_n = wid >> 1;   // 2x2 waves of 64x64
  const int l15 = lane & 15, quad = lane >> 4;
  const int m0 = blockIdx.y * 128, n0 = blockIdx.x * 128;

  // hoisted staging geometry: each thread covers 4 (row, c8) slots
  const _Float16* pA[4]; const _Float16* pB[4]; int ldsOff[4];
  #pragma unroll
  for (int r = 0; r < 4; ++r) {
    int flat = r * 256 + tid;            // 0..1023
    int row = flat >> 3, c8 = flat & 7;  // 8 x int4 per 64-elem k-slice
    int ga = m0 + row; if (ga > M_ROWS - 1) ga = M_ROWS - 1;
    int gb = n0 + row; if (gb > N_COLS - 1) gb = N_COLS - 1;
    pA[r] = A + (size_t)ga * K_DIM + c8 * 8;
    pB[r] = Bm + (size_t)gb * K_DIM + c8 * 8;
    ldsOff[r] = row * LDS_STR + c8 * 8;
  }

  floatx4 acc[4][4];
  floatx4 zz = {0.f, 0.f, 0.f, 0.f};
  #pragma unroll
  for (int mi = 0; mi < 4; ++mi)
    #pragma unroll
    for (int ni = 0; ni < 4; ++ni) acc[mi][ni] = zz;

  // pipeline prologue: k-chunk 0 into registers
  int4 avr[4], bvr[4];
  #pragma unroll
  for (int r = 0; r < 4; ++r) {
    avr[r] = *(const int4*)(pA[r]);
    bvr[r] = *(const int4*)(pB[r]);
  }

  for (int kk = 0; kk < K_DIM; kk += 64) {
    #pragma unroll
    for (int r = 0; r < 4; ++r) {
      *(int4*)(As + ldsOff[r]) = avr[r];
      *(int4*)(Bs + ldsOff[r]) = bvr[r];
    }
    __syncthreads();
    if (kk + 64 < K_DIM) {   // issue next chunk's loads NOW; consumed next iter
      #pragma unroll
      for (int r = 0; r < 4; ++r) {
        avr[r] = *(const int4*)(pA[r] + kk + 64);
        bvr[r] = *(const int4*)(pB[r] + kk + 64);
      }
    }
    #pragma unroll
    for (int ko = 0; ko < 64; ko += 32) {
      half8 af[4], bf[4];
      #pragma unroll
      for (int mi = 0; mi < 4; ++mi)
        af[mi] = *(const half8*)(As + (wave_m * 64 + mi * 16 + l15) * LDS_STR + ko + quad * 8);
      #pragma unroll
      for (int ni = 0; ni < 4; ++ni)
        bf[ni] = *(const half8*)(Bs + (wave_n * 64 + ni * 16 + l15) * LDS_STR + ko + quad * 8);
      #pragma unroll
      for (int mi = 0; mi < 4; ++mi)
        #pragma unroll
        for (int ni = 0; ni < 4; ++ni)
          acc[mi][ni] = __builtin_amdgcn_mfma_f32_16x16x32_f16(af[mi], bf[ni], acc[mi][ni], 0, 0, 0);
    }
    __syncthreads();
  }

  // ---- epilogue 1: bias + column masks ----
  float bvv[4]; bool cok[4];
  #pragma unroll
  for (int ni = 0; ni < 4; ++ni) {
    int col = n0 + wave_n * 64 + ni * 16 + l15;
    cok[ni] = (col < N_COLS);
    bvv[ni] = cok[ni] ? bias[col] : 0.f;
  }

  // ---- epilogue 2: ballot scatter of label logits (f16, base-2 pre-scaled) ------
  const int nbase = n0 + wave_n * 64;
  const int mbase = m0 + wave_m * 64;
  int b_lo = mbase / T_LEN;
  int b_hi = (mbase + 63) / T_LEN;
  if (b_hi > B_SZ - 1) b_hi = B_SZ - 1;
  for (int b = b_lo; b <= b_hi; ++b) {
    int v_l = 0x40000000;
    if (lane <= 50) v_l = (lane == 0) ? 0 : y[b * L_LAB + lane - 1];
    int dv_l = v_l - nbase;
    unsigned long long mask = __ballot(dv_l >= 0 && dv_l < 64);
    while (mask) {
      int j = (int)__builtin_ctzll(mask);
      mask &= mask - 1;
      int dv = __shfl(dv_l, j);          // wave-uniform
      int ni = dv >> 4;
      float bb = bvv[0];
      bb = (ni == 1) ? bvv[1] : bb;
      bb = (ni == 2) ? bvv[2] : bb;
      bb = (ni == 3) ? bvv[3] : bb;
      if ((dv & 15) == l15) {
        #pragma unroll
        for (int mi = 0; mi < 4; ++mi) {
          #pragma unroll
          for (int r = 0; r < 4; ++r) {
            float val = acc[mi][0][r];
            val = (ni == 1) ? acc[mi][1][r] : val;
            val = (ni == 2) ? acc[mi][2][r] : val;
            val = (ni == 3) ? acc[mi][3][r] : val;
            int grow = mbase + mi * 16 + quad * 4 + r;
            int t = grow - b * T_LEN;
            if (t >= 0 && t < T_LEN && grow < M_ROWS)
              lgT[((size_t)b * 51 + j) * T_PAD + t] = (_Float16)((val + bb) * LOG2E);
          }
        }
      }
    }
  }

  // ---- epilogue 3: per-row sum of e^logit, atomically accumulated ---------------
  #pragma unroll
  for (int mi = 0; mi < 4; ++mi) {
    #pragma unroll
    for (int r = 0; r < 4; ++r) {
      int grow = mbase + mi * 16 + quad * 4 + r;
      float se = 0.f;
      se += cok[0] ? fexp2((acc[mi][0][r] + bvv[0]) * LOG2E) : 0.f;
      se += cok[1] ? fexp2((acc[mi][1][r] + bvv[1]) * LOG2E) : 0.f;
      se += cok[2] ? fexp2((acc[mi][2][r] + bvv[2]) * LOG2E) : 0.f;
      se += cok[3] ? fexp2((acc[mi][3][r] + bvv[3]) * LOG2E) : 0.f;
      #pragma unroll
      for (int d = 1; d < 16; d <<= 1) se += __shfl_xor(se, d);
      if (l15 == 0 && grow < M_ROWS) atomicAdd(&psum[grow], se);
    }
  }
}

// ---------------- CTC forward DP: linear domain, f64, odds-vs-blank ---------------
// One block (256 thr) per batch element. Stage q(j,t) = 2^(l2[j]-l2[blank]) as f16
// in LDS (bank-friendly stride); parallel base2 = sum_t (l2_blank - log2 psum);
// wave 0 runs the 500-step recurrence: a0 += p1 ; a1 = (a1+a0+skip*p1)*q.
// Chain ~30cyc/step (no transcendentals). Correctness proven in R9/R10 (absmax 0).
__global__ __launch_bounds__(256) void k_dp(
    const _Float16* __restrict__ lgT, const float* __restrict__ psum,
    const int* __restrict__ enc_lens, const int* __restrict__ y,
    const int* __restrict__ y_lens, float* __restrict__ out) {
  __shared__ _Float16 sQ[50 * Q_STR];   // 52,000 B
  __shared__ float sRed[5];
  const int b = blockIdx.x, tid = threadIdx.x;
  const int Tb = enc_lens[b], yl = y_lens[b];
  const _Float16* g = lgT + (size_t)b * 51 * T_PAD;

  // stage q(label j+1, t)
  #pragma unroll
  for (int k = 0; k < 13; ++k) {
    int idx = tid + k * 256;
    if (idx < 50 * 64) {
      int row = idx >> 6, c8 = idx & 63;
      half8 h = *(const half8*)(g + (size_t)(row + 1) * T_PAD + c8 * 8);
      half8 hb = *(const half8*)(g + c8 * 8);
      half8 o;
      #pragma unroll
      for (int e = 0; e < 8; ++e)
        o[e] = (_Float16)fminf(fexp2((float)h[e] - (float)hb[e]), 60000.0f);
      *(half8*)(sQ + row * Q_STR + c8 * 8) = o;
    }
  }

  // parallel: base2 = sum_{t<Tb} (l2_blank[t] - log2(psum[b,t]))
  float sl2 = 0.f;
  for (int t = tid; t < Tb; t += 256)
    sl2 += (float)g[t] - flog2(psum[b * T_LEN + t]);
  #pragma unroll
  for (int d = 1; d < 64; d <<= 1) sl2 += __shfl_xor(sl2, d);
  if ((tid & 63) == 0) sRed[1 + (tid >> 6)] = sl2;
  __syncthreads();
  const float base2 = sRed[1] + sRed[2] + sRed[3] + sRed[4];

  if (tid < 64) {
    const int i = tid;
    const int rw = (i < 50) ? i : 49;
    const _Float16* ow = sQ + rw * Q_STR;
    const bool v1 = (i <= 49);
    const bool lane0 = (i == 0);
    const bool skip1 = (i >= 1 && i <= 49) && (y[b * L_LAB + i] != y[b * L_LAB + i - 1]);

    auto ld4 = [&](int t) -> double4 {
      half4 h = *(const half4*)(ow + t);
      double4 d;
      if (v1) { d.x = (float)h[0]; d.y = (float)h[1]; d.z = (float)h[2]; d.w = (float)h[3]; }
      else    { d.x = 0.0; d.y = 0.0; d.z = 0.0; d.w = 0.0; }
      return d;
    };
    double4 qA = ld4(0), qB = ld4(4), qC = ld4(8), qD = ld4(12);

    double a0 = lane0 ? 1.0 : 0.0;
    double a1 = lane0 ? qA.x : 0.0;

    auto step = [&](double qd) {
      double p1 = shr1_f64(a1);
      p1 = lane0 ? 0.0 : p1;
      double na0 = a0 + p1;
      double t3 = skip1 ? p1 : 0.0;
      double na1 = (a1 + a0 + t3) * qd;
      a0 = na0; a1 = na1;
    };

    step(qA.y); step(qA.z); step(qA.w);
    double4 cur = qB, nxt = qC, nn = qD;
    int t = 4;
    while (t + 4 <= Tb) {
      double4 p = ld4(t + 12);   // max index 511 < Q_STR, in-bounds
      step(cur.x); step(cur.y); step(cur.z); step(cur.w);
      cur = nxt; nxt = nn; nn = p;
      t += 4;
    }
    if (t < Tb) { step(cur.x); ++t; }
    if (t < Tb) { step(cur.y); ++t; }
    if (t < Tb) { step(cur.z); ++t; }

    double ea = __shfl(a0, yl);       // s = 2*yl
    double eb = __shfl(a1, yl - 1);   // s = 2*yl-1
    if (lane0) {
      double s = ea + eb;
      long long bb = __double_as_longlong(s);
      int e2 = (int)((bb >> 52) & 2047) - 1023;
      double mant = __longlong_as_double((bb & 0x000FFFFFFFFFFFFFLL) | 0x3FF0000000000000LL);
      float l2fin = (float)e2 + flog2((float)mant);
      atomicAdd(out, -(base2 + l2fin) * LN2 * (1.0f / (float)B_SZ));
    }
  }
}

extern "C" void kernel_launch(void* const* d_in, const int* in_sizes, int n_in,
                              void* d_out, int out_size, void* d_ws, size_t ws_size,
                              hipStream_t stream) {
  (void)in_sizes; (void)n_in; (void)out_size; (void)ws_size;
  const float* enc      = (const float*)d_in[0];   // [16][500][256]
  const int*   enc_lens = (const int*)d_in[1];     // [16]
  const int*   y        = (const int*)d_in[2];     // [16][50]
  const int*   y_lens   = (const int*)d_in[3];     // [16]
  const float* W        = (const float*)d_in[4];   // [5000][256]
  const float* bias     = (const float*)d_in[5];   // [5000]
  float* out = (float*)d_out;

  char* ws = (char*)d_ws;
  _Float16* ench = (_Float16*)(ws + 0);            // 4,096,000 B
  _Float16* wh   = (_Float16*)(ws + 4096000);      // 2,560,000 B
  float* psum    = (float*)(ws + 6656000);         //    32,000 B
  _Float16* lgT  = (_Float16*)(ws + 6688000);      //   835,584 B

  k_f2h2<<<3250, 256, 0, stream>>>(enc, W, ench, wh, out, psum);
  k_gemm_lse<<<dim3(40, 63), 256, 0, stream>>>(ench, wh, bias, y, psum, lgT);
  k_dp<<<16, 256, 0, stream>>>(lgT, psum, enc_lens, y, y_lens, out);
}

// Round 12
// 192.759 us; speedup vs baseline: 1.7325x; 1.2236x over previous
//
#include <hip/hip_runtime.h>
#include <hip/hip_bf16.h>

#define NEG (-1e30f)
#define M_ROWS 8000   // B*T = 16*500
#define N_COLS 5000   // V
#define K_DIM  256    // D
#define T_LEN  500
#define T_PAD  512    // lgT inner stride (t), f16 elems
#define B_SZ   16
#define L_LAB  50
#define LDS_STR 72    // gemm LDS pad (f16 elems)
#define Q_STR  520    // k_dp sQ row stride (f16): b64 reads 8-way, not 64-way
#define LOG2E  1.4426950408889634f
#define LN2    0.6931471805599453f

typedef _Float16 half8  __attribute__((ext_vector_type(8)));
typedef _Float16 half4  __attribute__((ext_vector_type(4)));
typedef _Float16 half4v __attribute__((ext_vector_type(4)));
typedef float    floatx4 __attribute__((ext_vector_type(4)));

__device__ __forceinline__ float fexp2(float x) {
#if defined(__has_builtin)
#if __has_builtin(__builtin_amdgcn_exp2f)
  return __builtin_amdgcn_exp2f(x);
#else
  return __expf(x * LN2);
#endif
#else
  return __expf(x * LN2);
#endif
}
__device__ __forceinline__ float flog2(float x) {
#if defined(__has_builtin)
#if __has_builtin(__builtin_amdgcn_logf)
  return __builtin_amdgcn_logf(x);
#else
  return __logf(x) * LOG2E;
#endif
#else
  return __logf(x) * LOG2E;
#endif
}
// cross-lane shift-down-by-1 (lane i <- lane i-1), lane0 -> 0.0, for doubles
__device__ __forceinline__ double shr1_f64(double x) {
#if defined(__has_builtin)
#if __has_builtin(__builtin_amdgcn_update_dpp)
  long long b = __double_as_longlong(x);
  int lo = (int)(b & 0xffffffffLL);
  int hi = (int)(((unsigned long long)b) >> 32);
  lo = __builtin_amdgcn_update_dpp(0, lo, 0x138 /*wave_shr:1*/, 0xf, 0xf, false);
  hi = __builtin_amdgcn_update_dpp(0, hi, 0x138 /*wave_shr:1*/, 0xf, 0xf, false);
  return __longlong_as_double(((long long)(unsigned)hi << 32) | (unsigned)lo);
#else
  return __shfl_up(x, 1);
#endif
#else
  return __shfl_up(x, 1);
#endif
}

// ---------------- fused fp32->fp16 (enc + W) + zero out/psum ----------------------
__global__ void k_f2h2(const float* __restrict__ enc, const float* __restrict__ W,
                       _Float16* __restrict__ ench, _Float16* __restrict__ wh,
                       float* z, float* psum) {
  int i = blockIdx.x * blockDim.x + threadIdx.x;
  if (i == 0) z[0] = 0.0f;
  if (i < M_ROWS) psum[i] = 0.0f;
  if (i < 512000) {
    float4 v = ((const float4*)enc)[i];
    half4v o = {(_Float16)v.x, (_Float16)v.y, (_Float16)v.z, (_Float16)v.w};
    ((half4v*)ench)[i] = o;
  } else {
    int k = i - 512000;
    if (k < 320000) {
      float4 v = ((const float4*)W)[k];
      half4v o = {(_Float16)v.x, (_Float16)v.y, (_Float16)v.z, (_Float16)v.w};
      ((half4v*)wh)[k] = o;
    }
  }
}

// ---------------- MFMA GEMM: R7 body + A-only register prefetch -------------------
// R11's full pipeline (8 int4 data + 8 hoisted pointers held across MFMA) spilled
// to scratch: WRITE_SIZE 10.8 -> 235 MB, gemm 78 -> 145us. This version holds ONLY
// 4 int4 (A prefetch, 16 VGPRs); all addresses recomputed per-iter like R7.
__global__ __launch_bounds__(256) void k_gemm_lse(
    const _Float16* __restrict__ A, const _Float16* __restrict__ Bm,
    const float* __restrict__ bias, const int* __restrict__ y,
    float* __restrict__ psum, _Float16* __restrict__ lgT) {
  __shared__ _Float16 As[128 * LDS_STR];   // 18,432 B
  __shared__ _Float16 Bs[128 * LDS_STR];   // 18,432 B

  const int tid = threadIdx.x;
  const int lane = tid & 63;
  const int wid = tid >> 6;
  const int wave_m = wid & 1, wave_n = wid >> 1;   // 2x2 waves of 64x64
  const int l15 = lane & 15, quad = lane >> 4;
  const int m0 = blockIdx.y * 128, n0 = blockIdx.x * 128;

  floatx4 acc[4][4];
  floatx4 zz = {0.f, 0.f, 0.f, 0.f};
  #pragma unroll
  for (int mi = 0; mi < 4; ++mi)
    #pragma unroll
    for (int ni = 0; ni < 4; ++ni) acc[mi][ni] = zz;

  // prologue: A k-chunk 0 into registers (16 VGPRs held)
  int4 avr[4];
  #pragma unroll
  for (int r = 0; r < 4; ++r) {
    int flat = r * 256 + tid;
    int row = flat >> 3, c8 = flat & 7;
    int ga = m0 + row; if (ga > M_ROWS - 1) ga = M_ROWS - 1;
    avr[r] = *(const int4*)(A + (size_t)ga * K_DIM + c8 * 8);
  }

  for (int kk = 0; kk < K_DIM; kk += 64) {
    #pragma unroll
    for (int r = 0; r < 4; ++r) {
      int flat = r * 256 + tid;            // 0..1023
      int row = flat >> 3, c8 = flat & 7;  // 8 x int4 per 64-elem k-slice
      int gb = n0 + row; if (gb > N_COLS - 1) gb = N_COLS - 1;
      int4 bv = *(const int4*)(Bm + (size_t)gb * K_DIM + kk + c8 * 8);
      *(int4*)(As + row * LDS_STR + c8 * 8) = avr[r];
      *(int4*)(Bs + row * LDS_STR + c8 * 8) = bv;
    }
    __syncthreads();
    if (kk + 64 < K_DIM) {   // A chunk kk+64: in flight across the MFMA section
      #pragma unroll
      for (int r = 0; r < 4; ++r) {
        int flat = r * 256 + tid;
        int row = flat >> 3, c8 = flat & 7;
        int ga = m0 + row; if (ga > M_ROWS - 1) ga = M_ROWS - 1;
        avr[r] = *(const int4*)(A + (size_t)ga * K_DIM + kk + 64 + c8 * 8);
      }
    }
    #pragma unroll
    for (int ko = 0; ko < 64; ko += 32) {
      half8 af[4], bf[4];
      #pragma unroll
      for (int mi = 0; mi < 4; ++mi)
        af[mi] = *(const half8*)(As + (wave_m * 64 + mi * 16 + l15) * LDS_STR + ko + quad * 8);
      #pragma unroll
      for (int ni = 0; ni < 4; ++ni)
        bf[ni] = *(const half8*)(Bs + (wave_n * 64 + ni * 16 + l15) * LDS_STR + ko + quad * 8);
      #pragma unroll
      for (int mi = 0; mi < 4; ++mi)
        #pragma unroll
        for (int ni = 0; ni < 4; ++ni)
          acc[mi][ni] = __builtin_amdgcn_mfma_f32_16x16x32_f16(af[mi], bf[ni], acc[mi][ni], 0, 0, 0);
    }
    __syncthreads();
  }

  // ---- epilogue 1: bias + column masks ----
  float bvv[4]; bool cok[4];
  #pragma unroll
  for (int ni = 0; ni < 4; ++ni) {
    int col = n0 + wave_n * 64 + ni * 16 + l15;
    cok[ni] = (col < N_COLS);
    bvv[ni] = cok[ni] ? bias[col] : 0.f;
  }

  // ---- epilogue 2: ballot scatter of label logits (f16, base-2 pre-scaled) ------
  const int nbase = n0 + wave_n * 64;
  const int mbase = m0 + wave_m * 64;
  int b_lo = mbase / T_LEN;
  int b_hi = (mbase + 63) / T_LEN;
  if (b_hi > B_SZ - 1) b_hi = B_SZ - 1;
  for (int b = b_lo; b <= b_hi; ++b) {
    int v_l = 0x40000000;
    if (lane <= 50) v_l = (lane == 0) ? 0 : y[b * L_LAB + lane - 1];
    int dv_l = v_l - nbase;
    unsigned long long mask = __ballot(dv_l >= 0 && dv_l < 64);
    while (mask) {
      int j = (int)__builtin_ctzll(mask);
      mask &= mask - 1;
      int dv = __shfl(dv_l, j);          // wave-uniform
      int ni = dv >> 4;
      float bb = bvv[0];
      bb = (ni == 1) ? bvv[1] : bb;
      bb = (ni == 2) ? bvv[2] : bb;
      bb = (ni == 3) ? bvv[3] : bb;
      if ((dv & 15) == l15) {
        #pragma unroll
        for (int mi = 0; mi < 4; ++mi) {
          #pragma unroll
          for (int r = 0; r < 4; ++r) {
            float val = acc[mi][0][r];
            val = (ni == 1) ? acc[mi][1][r] : val;
            val = (ni == 2) ? acc[mi][2][r] : val;
            val = (ni == 3) ? acc[mi][3][r] : val;
            int grow = mbase + mi * 16 + quad * 4 + r;
            int t = grow - b * T_LEN;
            if (t >= 0 && t < T_LEN && grow < M_ROWS)
              lgT[((size_t)b * 51 + j) * T_PAD + t] = (_Float16)((val + bb) * LOG2E);
          }
        }
      }
    }
  }

  // ---- epilogue 3: per-row sum of e^logit, atomically accumulated ---------------
  #pragma unroll
  for (int mi = 0; mi < 4; ++mi) {
    #pragma unroll
    for (int r = 0; r < 4; ++r) {
      int grow = mbase + mi * 16 + quad * 4 + r;
      float se = 0.f;
      se += cok[0] ? fexp2((acc[mi][0][r] + bvv[0]) * LOG2E) : 0.f;
      se += cok[1] ? fexp2((acc[mi][1][r] + bvv[1]) * LOG2E) : 0.f;
      se += cok[2] ? fexp2((acc[mi][2][r] + bvv[2]) * LOG2E) : 0.f;
      se += cok[3] ? fexp2((acc[mi][3][r] + bvv[3]) * LOG2E) : 0.f;
      #pragma unroll
      for (int d = 1; d < 16; d <<= 1) se += __shfl_xor(se, d);
      if (l15 == 0 && grow < M_ROWS) atomicAdd(&psum[grow], se);
    }
  }
}

// ---------------- CTC forward DP: linear domain, f64, odds-vs-blank ---------------
// (proven absmax 0.0 in R9/R10/R11)
__global__ __launch_bounds__(256) void k_dp(
    const _Float16* __restrict__ lgT, const float* __restrict__ psum,
    const int* __restrict__ enc_lens, const int* __restrict__ y,
    const int* __restrict__ y_lens, float* __restrict__ out) {
  __shared__ _Float16 sQ[50 * Q_STR];   // 52,000 B
  __shared__ float sRed[5];
  const int b = blockIdx.x, tid = threadIdx.x;
  const int Tb = enc_lens[b], yl = y_lens[b];
  const _Float16* g = lgT + (size_t)b * 51 * T_PAD;

  // stage q(label j+1, t) = 2^(l2[j+1][t] - l2[0][t]) as f16
  #pragma unroll
  for (int k = 0; k < 13; ++k) {
    int idx = tid + k * 256;
    if (idx < 50 * 64) {
      int row = idx >> 6, c8 = idx & 63;
      half8 h = *(const half8*)(g + (size_t)(row + 1) * T_PAD + c8 * 8);
      half8 hb = *(const half8*)(g + c8 * 8);
      half8 o;
      #pragma unroll
      for (int e = 0; e < 8; ++e)
        o[e] = (_Float16)fminf(fexp2((float)h[e] - (float)hb[e]), 60000.0f);
      *(half8*)(sQ + row * Q_STR + c8 * 8) = o;
    }
  }

  // parallel: base2 = sum_{t<Tb} (l2_blank[t] - log2(psum[b,t]))
  float sl2 = 0.f;
  for (int t = tid; t < Tb; t += 256)
    sl2 += (float)g[t] - flog2(psum[b * T_LEN + t]);
  #pragma unroll
  for (int d = 1; d < 64; d <<= 1) sl2 += __shfl_xor(sl2, d);
  if ((tid & 63) == 0) sRed[1 + (tid >> 6)] = sl2;
  __syncthreads();
  const float base2 = sRed[1] + sRed[2] + sRed[3] + sRed[4];

  if (tid < 64) {
    const int i = tid;
    const int rw = (i < 50) ? i : 49;
    const _Float16* ow = sQ + rw * Q_STR;
    const bool v1 = (i <= 49);
    const bool lane0 = (i == 0);
    const bool skip1 = (i >= 1 && i <= 49) && (y[b * L_LAB + i] != y[b * L_LAB + i - 1]);

    auto ld4 = [&](int t) -> double4 {
      half4 h = *(const half4*)(ow + t);
      double4 d;
      if (v1) { d.x = (float)h[0]; d.y = (float)h[1]; d.z = (float)h[2]; d.w = (float)h[3]; }
      else    { d.x = 0.0; d.y = 0.0; d.z = 0.0; d.w = 0.0; }
      return d;
    };
    double4 qA = ld4(0), qB = ld4(4), qC = ld4(8), qD = ld4(12);

    double a0 = lane0 ? 1.0 : 0.0;
    double a1 = lane0 ? qA.x : 0.0;

    auto step = [&](double qd) {
      double p1 = shr1_f64(a1);
      p1 = lane0 ? 0.0 : p1;
      double na0 = a0 + p1;
      double t3 = skip1 ? p1 : 0.0;
      double na1 = (a1 + a0 + t3) * qd;
      a0 = na0; a1 = na1;
    };

    step(qA.y); step(qA.z); step(qA.w);
    double4 cur = qB, nxt = qC, nn = qD;
    int t = 4;
    while (t + 4 <= Tb) {
      double4 p = ld4(t + 12);   // max index 511 < Q_STR, in-bounds
      step(cur.x); step(cur.y); step(cur.z); step(cur.w);
      cur = nxt; nxt = nn; nn = p;
      t += 4;
    }
    if (t < Tb) { step(cur.x); ++t; }
    if (t < Tb) { step(cur.y); ++t; }
    if (t < Tb) { step(cur.z); ++t; }

    double ea = __shfl(a0, yl);       // s = 2*yl
    double eb = __shfl(a1, yl - 1);   // s = 2*yl-1
    if (lane0) {
      double s = ea + eb;
      long long bb = __double_as_longlong(s);
      int e2 = (int)((bb >> 52) & 2047) - 1023;
      double mant = __longlong_as_double((bb & 0x000FFFFFFFFFFFFFLL) | 0x3FF0000000000000LL);
      float l2fin = (float)e2 + flog2((float)mant);
      atomicAdd(out, -(base2 + l2fin) * LN2 * (1.0f / (float)B_SZ));
    }
  }
}

extern "C" void kernel_launch(void* const* d_in, const int* in_sizes, int n_in,
                              void* d_out, int out_size, void* d_ws, size_t ws_size,
                              hipStream_t stream) {
  (void)in_sizes; (void)n_in; (void)out_size; (void)ws_size;
  const float* enc      = (const float*)d_in[0];   // [16][500][256]
  const int*   enc_lens = (const int*)d_in[1];     // [16]
  const int*   y        = (const int*)d_in[2];     // [16][50]
  const int*   y_lens   = (const int*)d_in[3];     // [16]
  const float* W        = (const float*)d_in[4];   // [5000][256]
  const float* bias     = (const float*)d_in[5];   // [5000]
  float* out = (float*)d_out;

  char* ws = (char*)d_ws;
  _Float16* ench = (_Float16*)(ws + 0);            // 4,096,000 B
  _Float16* wh   = (_Float16*)(ws + 4096000);      // 2,560,000 B
  float* psum    = (float*)(ws + 6656000);         //    32,000 B
  _Float16* lgT  = (_Float16*)(ws + 6688000);      //   835,584 B

  k_f2h2<<<3250, 256, 0, stream>>>(enc, W, ench, wh, out, psum);
  k_gemm_lse<<<dim3(40, 63), 256, 0, stream>>>(ench, wh, bias, y, psum, lgT);
  k_dp<<<16, 256, 0, stream>>>(lgT, psum, enc_lens, y, y_lens, out);
}